// Round 4
// baseline (239.324 us; speedup 1.0000x reference)
//
#include <hip/hip_runtime.h>

// NTN: out[n,k] = relu( cos(x1 @ W1[k], x2 @ W2[k]) + [x1,x2]·V[k] + b[k] )
// N=32768, D=128, K=16.
// R4: 32x32x16 MFMA (A-frag feeds 2x the MACs of 16x16x32 -> halves LDS read
// traffic per wave; halves MFMA instr count). Block: 256 thr / 4 waves,
// 256 rows/block, 64 rows/wave (2 row-tiles of 32 -> xb still 64 VGPRs).
// Grid 512 = (rb 0..127) x (kh 0..3), k-range 4, 2 blocks/CU (64KB LDS each).
// Chunk cc=k*2+h (32KB): both sides, e-half h (2 e-tiles of 32), 8 d-steps of 16.
// Per k: ping-pong 2 chunks via global_load_lds; T1/T2 tiles back-to-back,
// folded immediately into nm/q1/q2 (16-reg in-lane fold + single shfl_xor(32)).
// part2+b: 32x32x16 MFMA with zero-padded V A-frags (C rows m<16 = k), kept in regs.

typedef __attribute__((ext_vector_type(8))) __bf16 bf16x8;
typedef __attribute__((ext_vector_type(8))) unsigned short us8;
typedef __attribute__((ext_vector_type(16))) float f32x16;

static __device__ __forceinline__ unsigned short f2bf(float f) {
  unsigned u = __float_as_uint(f);
  u += 0x7FFFu + ((u >> 16) & 1u);   // round-to-nearest-even
  return (unsigned short)(u >> 16);
}

static __device__ __forceinline__ bf16x8 as_bf(us8 u) {
  bf16x8 r;
  __builtin_memcpy(&r, &u, sizeof(r));
  return r;
}

// ---------------- prep ----------------
// wsW: 32 chunks (cc = k*2 + h) of 2048 16B-units (32KB).
//   unit u: side=(u>>10)&1, et2=(u>>9)&1, s=(u>>6)&7, lane=u&63.
//   frag[j] = W_side[k][d = s*16 + (lane>>5)*8 + j][e = (h*2+et2)*32 + (lane&31)]
//   (A-operand of 32x32x16: m = lane&31, kdim = (lane>>5)*8 + j)
// wsV: 16 units-groups: unit ss*64+lane:
//   frag[j] = (lane&31)<16 ? V[m=lane&31][c = ss*16 + (lane>>5)*8 + j] : 0
__global__ void ntn_prep(const float* __restrict__ W1, const float* __restrict__ W2,
                         const float* __restrict__ V,
                         unsigned short* __restrict__ wsW, unsigned short* __restrict__ wsV) {
  int t = blockIdx.x * 256 + threadIdx.x;
  if (t < 65536) {
    int u = t & 2047;
    int lane = u & 63, s = (u >> 6) & 7, et2 = (u >> 9) & 1, side = (u >> 10) & 1;
    int cc = t >> 11, h = cc & 1, k = cc >> 1;
    int hh = lane >> 5, l31 = lane & 31;
    int e = (h * 2 + et2) * 32 + l31;
    int d0 = s * 16 + hh * 8;
    const float* W = side ? W2 : W1;
    const float* src = W + k * 16384 + d0 * 128 + e;
    us8 r;
#pragma unroll
    for (int j = 0; j < 8; ++j) r[j] = f2bf(src[j * 128]);
    *(us8*)(wsW + (size_t)t * 8) = r;
  } else if (t < 66560) {
    int u = t - 65536;               // 0..1023
    int lane = u & 63, ss = u >> 6;
    int hh = lane >> 5, l31 = lane & 31;
    us8 r;
    if (l31 < 16) {
      const float* src = V + l31 * 256 + ss * 16 + hh * 8;
#pragma unroll
      for (int j = 0; j < 8; ++j) r[j] = f2bf(src[j]);
    } else {
#pragma unroll
      for (int j = 0; j < 8; ++j) r[j] = 0;
    }
    *(us8*)(wsV + (size_t)u * 8) = r;
  }
}

// ---------------- main ----------------
__global__ __launch_bounds__(256, 2) void ntn_main(
    const float* __restrict__ x1, const float* __restrict__ x2,
    const float* __restrict__ b,
    const unsigned short* __restrict__ wsW, const unsigned short* __restrict__ wsV,
    float* __restrict__ out) {
  __shared__ uint4 ldsW[2][2048];   // two 32KB chunk slots = 64KB

  const int tid = threadIdx.x;
  const int lane = tid & 63, wave = tid >> 6;
  const int hh = lane >> 5, l31 = lane & 31;
  const int kh = blockIdx.x & 3;          // k range [4kh, 4kh+4)
  const int rb = blockIdx.x >> 2;         // 256-row group
  const int rowbase = rb * 256 + wave * 64;

  const f32x16 zero16 = {0.f};

  // async stage of one 32KB chunk into an LDS slot (8 glds x 64 lanes x 16B / wave)
  auto stage = [&](int cc, int slot) {
    const unsigned short* src = wsW + (size_t)cc * 16384 + (size_t)(wave * 512 + lane) * 8;
    uint4* dst = &ldsW[slot][wave * 512];
#pragma unroll
    for (int i = 0; i < 8; ++i)
      __builtin_amdgcn_global_load_lds(
          (__attribute__((address_space(1))) void*)(void*)(src + i * 512),
          (__attribute__((address_space(3))) void*)(dst + i * 64), 16, 0, 0);
  };

  stage(kh * 8, 0);   // first chunk of our k range

  // ---- X fragments (B-operand of 32x32x16: n=lane&31, kdim=(lane>>5)*8+j) ----
  // frag[j] = X[row = rowbase + nt*32 + l31][d = s*16 + hh*8 + j]
  bf16x8 xb[2][2][8];
#pragma unroll
  for (int side = 0; side < 2; ++side) {
    const float* xp0 = side ? x2 : x1;
#pragma unroll
    for (int nt = 0; nt < 2; ++nt) {
#pragma unroll
      for (int s = 0; s < 8; ++s) {
        const float* p = xp0 + (size_t)(rowbase + nt * 32 + l31) * 128 + s * 16 + hh * 8;
        float4 v0 = *(const float4*)p;
        float4 v1 = *(const float4*)(p + 4);
        us8 uu;
        uu[0] = f2bf(v0.x); uu[1] = f2bf(v0.y); uu[2] = f2bf(v0.z); uu[3] = f2bf(v0.w);
        uu[4] = f2bf(v1.x); uu[5] = f2bf(v1.y); uu[6] = f2bf(v1.z); uu[7] = f2bf(v1.w);
        xb[side][nt][s] = as_bf(uu);
      }
    }
  }

  // ---- part2 via 32x32x16 MFMA (A = zero-padded V frags: m=k; B = X frags) ----
  // C row m = (r&3) + 8*(r>>2) + 4*hh; only m<16 (r<8) kept.
  float accP[2][8];
  {
#pragma unroll
    for (int nt = 0; nt < 2; ++nt) {
      f32x16 c = zero16;
#pragma unroll
      for (int ss = 0; ss < 16; ++ss) {
        bf16x8 vf = as_bf(*(const us8*)(wsV + (size_t)(ss * 64 + lane) * 8));
        c = __builtin_amdgcn_mfma_f32_32x32x16_bf16(vf, xb[ss >> 3][nt][ss & 7], c, 0, 0, 0);
      }
#pragma unroll
      for (int r = 0; r < 8; ++r) accP[nt][r] = c[r];
    }
  }

  float nm[2] = {0.f, 0.f}, q1[2] = {0.f, 0.f}, q2[2] = {0.f, 0.f};

  // compute one chunk (2 e-tiles of 32, both sides) from an LDS slot, fold reductions
  auto compute = [&](int slot) {
#pragma unroll
    for (int et = 0; et < 2; ++et) {
      bf16x8 wa[8], wb[8];
#pragma unroll
      for (int s = 0; s < 8; ++s) {
        wa[s] = as_bf(*(const us8*)&ldsW[slot][et * 512 + s * 64 + lane]);
        wb[s] = as_bf(*(const us8*)&ldsW[slot][1024 + et * 512 + s * 64 + lane]);
      }
#pragma unroll
      for (int nt = 0; nt < 2; ++nt) {
        f32x16 a1 = zero16, a2 = zero16;
#pragma unroll
        for (int s = 0; s < 8; ++s)
          a1 = __builtin_amdgcn_mfma_f32_32x32x16_bf16(wa[s], xb[0][nt][s], a1, 0, 0, 0);
#pragma unroll
        for (int s = 0; s < 8; ++s)
          a2 = __builtin_amdgcn_mfma_f32_32x32x16_bf16(wb[s], xb[1][nt][s], a2, 0, 0, 0);
        float n = 0.f, s1 = 0.f, s2 = 0.f;
#pragma unroll
        for (int r = 0; r < 16; ++r) {
          n  += a1[r] * a2[r];
          s1 += a1[r] * a1[r];
          s2 += a2[r] * a2[r];
        }
        nm[nt] += n; q1[nt] += s1; q2[nt] += s2;
      }
    }
  };

#pragma unroll 1
  for (int kk = 0; kk < 4; ++kk) {
    const int cbase = kh * 8 + 2 * kk;
    __syncthreads();                       // chunk (kk, h=0) in slot0; slot1 free
    stage(cbase + 1, 1);
    compute(0);
    __syncthreads();                       // chunk (kk, h=1) in slot1; slot0 free
    if (kk < 3) stage(cbase + 2, 0);
    compute(1);

    const int k = kh * 4 + kk;
    const float bk = b[k];
    const int ho = (k >> 2) & 1;           // owning lane half
    const int ri = (k & 3) + 4 * (k >> 3); // accP reg index
#pragma unroll
    for (int nt = 0; nt < 2; ++nt) {
      float n = nm[nt], s1 = q1[nt], s2 = q2[nt];
      n  += __shfl_xor(n, 32);
      s1 += __shfl_xor(s1, 32);
      s2 += __shfl_xor(s2, 32);
      float d1 = fmaxf(sqrtf(s1), 1e-8f);
      float d2 = fmaxf(sqrtf(s2), 1e-8f);
      float p1 = n / (d1 * d2);
      if (hh == ho)
        out[(size_t)(rowbase + nt * 32 + l31) * 16 + k] =
            fmaxf(p1 + accP[nt][ri] + bk, 0.f);
      nm[nt] = 0.f; q1[nt] = 0.f; q2[nt] = 0.f;
    }
  }
}

extern "C" void kernel_launch(void* const* d_in, const int* in_sizes, int n_in,
                              void* d_out, int out_size, void* d_ws, size_t ws_size,
                              hipStream_t stream) {
  const float* x1 = (const float*)d_in[0];
  const float* x2 = (const float*)d_in[1];
  const float* W1 = (const float*)d_in[2];
  const float* W2 = (const float*)d_in[3];
  const float* V  = (const float*)d_in[4];
  const float* b  = (const float*)d_in[5];
  float* out = (float*)d_out;
  unsigned short* wsW = (unsigned short*)d_ws;
  unsigned short* wsV = wsW + (size_t)65536 * 8;   // 1MB offset

  ntn_prep<<<260, 256, 0, stream>>>(W1, W2, V, wsW, wsV);
  ntn_main<<<512, 256, 0, stream>>>(x1, x2, b, wsW, wsV, out);
}

// Round 5
// 144.758 us; speedup vs baseline: 1.6533x; 1.6533x over previous
//
#include <hip/hip_runtime.h>

// NTN: out[n,k] = relu( cos(x1 @ W1[k], x2 @ W2[k]) + [x1,x2]·V[k] + b[k] )
// N=32768, D=128, K=16.
// R5:
//  - prep_w: coalesced LDS-transpose swizzle of W -> bf16 16x16x32 A-frags.
//    64 blocks = (k, side, e-half). Fixes R1-R4's ~60us uncoalesced prep.
//  - main: 16x16x32 MFMA, nt=4 (64 rows/wave, xb=128 VGPRs), 256 rows/block,
//    grid 512 = (rb 0..127) x (kh 0..3), 2 blocks/CU (64KB LDS), 8 waves/CU.
//    Chunk cc=k*2+h (32KB) holds both sides of e-half h. Per k: 2 chunks
//    ping-pong via global_load_lds; products folded immediately (no acc1).
//    kk-loop FULLY UNROLLED; part2+b lives in f32x4 accP[nt] (lanes q==kh own
//    k=4kh+reg via C-layout) -- all indexing static, no dynamic-index arrays
//    (R4's accP[ri] got LDS-lowered: +16KB LDS, 442K bank conflicts, spills).

typedef __attribute__((ext_vector_type(8))) __bf16 bf16x8;
typedef __attribute__((ext_vector_type(8))) unsigned short us8;
typedef __attribute__((ext_vector_type(4))) float f32x4;

static __device__ __forceinline__ unsigned short f2bf(float f) {
  unsigned u = __float_as_uint(f);
  u += 0x7FFFu + ((u >> 16) & 1u);   // round-to-nearest-even
  return (unsigned short)(u >> 16);
}

static __device__ __forceinline__ bf16x8 as_bf(us8 u) {
  bf16x8 r;
  __builtin_memcpy(&r, &u, sizeof(r));
  return r;
}

// ---------------- prep_w: coalesced transpose-swizzle ----------------
// wsW: 32 chunks (cc = k*2 + h) of 2048 16B-units (32KB).
//   unit u: side=(u>>10)&1, et2=(u>>8)&3, s=(u>>6)&3, lane=u&63.
//   frag[j] = W_side[k][d = s*32 + (lane>>4)*8 + j][e = h*64 + et2*16 + (lane&15)]
// Grid: 64 blocks: k = b>>2, side = (b>>1)&1, h = b&1. 256 threads.
__global__ void ntn_prep_w(const float* __restrict__ W1, const float* __restrict__ W2,
                           unsigned short* __restrict__ wsW) {
  __shared__ float T[128 * 68];   // row stride 68 floats: 16B-aligned rows, 2-way banks on col reads
  const int t = threadIdx.x;
  const int blk = blockIdx.x;
  const int k = blk >> 2, side = (blk >> 1) & 1, h = blk & 1;
  const float* W = (side ? W2 : W1) + k * 16384 + h * 64;

  // load: 128 d-rows x 64 e (32KB f32), coalesced float4
#pragma unroll
  for (int i = 0; i < 8; ++i) {
    int fidx = i * 256 + t;          // 0..2047
    int d = fidx >> 4, c4 = fidx & 15;
    float4 v = *(const float4*)(W + d * 128 + c4 * 4);
    *(float4*)&T[d * 68 + c4 * 4] = v;
  }
  __syncthreads();

  // emit: 1024 us8 units, contiguous global stores
  const size_t base = ((size_t)(k * 2 + h) * 2048 + side * 1024) * 8;
#pragma unroll
  for (int ui = 0; ui < 4; ++ui) {
    int u = ui * 256 + t;            // 0..1023
    int lane = u & 63, s = (u >> 6) & 3, et2 = (u >> 8) & 3;
    int q = lane >> 4, l15 = lane & 15;
    int d0 = s * 32 + q * 8, e = et2 * 16 + l15;
    us8 r;
#pragma unroll
    for (int j = 0; j < 8; ++j) r[j] = f2bf(T[(d0 + j) * 68 + e]);
    *(us8*)(wsW + base + (size_t)u * 8) = r;
  }
}

// ---------------- prep_v ----------------
// wsV: unit cs*64+lane: frag[j] = V[lane&15][c = cs*32 + (lane>>4)*8 + j]
__global__ void ntn_prep_v(const float* __restrict__ V, unsigned short* __restrict__ wsV) {
  int u = blockIdx.x * 256 + threadIdx.x;   // 0..1023
  if (u < 512) {
    int lane = u & 63, cs = u >> 6;
    int q = lane >> 4, l15 = lane & 15;
    const float* src = V + l15 * 256 + cs * 32 + q * 8;
    us8 r;
#pragma unroll
    for (int j = 0; j < 8; ++j) r[j] = f2bf(src[j]);
    *(us8*)(wsV + (size_t)u * 8) = r;
  }
}

// ---------------- main ----------------
__global__ __launch_bounds__(256, 2) void ntn_main(
    const float* __restrict__ x1, const float* __restrict__ x2,
    const float* __restrict__ b,
    const unsigned short* __restrict__ wsW, const unsigned short* __restrict__ wsV,
    float* __restrict__ out) {
  __shared__ uint4 ldsW[2][2048];   // two 32KB chunk slots = 64KB

  const int tid = threadIdx.x;
  const int lane = tid & 63, wave = tid >> 6;
  const int q = lane >> 4, l15 = lane & 15;
  const int kh = blockIdx.x & 3;          // k range [4kh, 4kh+4)
  const int rb = blockIdx.x >> 2;         // 256-row group
  const int rowbase = rb * 256 + wave * 64;

  const f32x4 zero4 = {0.f, 0.f, 0.f, 0.f};

  auto stage = [&](int cc, int slot) {
    const unsigned short* src = wsW + (size_t)cc * 16384 + (size_t)(wave * 512 + lane) * 8;
    uint4* dst = &ldsW[slot][wave * 512];
#pragma unroll
    for (int i = 0; i < 8; ++i)
      __builtin_amdgcn_global_load_lds(
          (__attribute__((address_space(1))) void*)(void*)(src + i * 512),
          (__attribute__((address_space(3))) void*)(dst + i * 64), 16, 0, 0);
  };

  stage(kh * 8, 0);   // first chunk of our k range

  // ---- X fragments (B-operand): frag[j] = X[rowbase+nt*16+l15][d = s*32+q*8+j] ----
  bf16x8 xb[2][4][4];   // [side][nt][s] = 128 VGPRs
#pragma unroll
  for (int side = 0; side < 2; ++side) {
    const float* xp0 = side ? x2 : x1;
#pragma unroll
    for (int nt = 0; nt < 4; ++nt) {
#pragma unroll
      for (int s = 0; s < 4; ++s) {
        const float* p = xp0 + (size_t)(rowbase + nt * 16 + l15) * 128 + s * 32 + q * 8;
        float4 v0 = *(const float4*)p;
        float4 v1 = *(const float4*)(p + 4);
        us8 uu;
        uu[0] = f2bf(v0.x); uu[1] = f2bf(v0.y); uu[2] = f2bf(v0.z); uu[3] = f2bf(v0.w);
        uu[4] = f2bf(v1.x); uu[5] = f2bf(v1.y); uu[6] = f2bf(v1.z); uu[7] = f2bf(v1.w);
        xb[side][nt][s] = as_bf(uu);
      }
    }
  }

  // ---- part2 + b via MFMA (A = V frags: M=k; B = X frags); lanes q==kh own k=4kh+reg ----
  f32x4 accP[4];
  {
    float4 bv = *(const float4*)(b + q * 4);
#pragma unroll
    for (int nt = 0; nt < 4; ++nt) {
      f32x4 a = zero4;
#pragma unroll
      for (int cs = 0; cs < 8; ++cs) {
        bf16x8 vf = as_bf(*(const us8*)(wsV + (size_t)(cs * 64 + lane) * 8));
        a = __builtin_amdgcn_mfma_f32_16x16x32_bf16(vf, xb[cs >> 2][nt][cs & 3], a, 0, 0, 0);
      }
      a.x += bv.x; a.y += bv.y; a.z += bv.z; a.w += bv.w;
      accP[nt] = a;
    }
  }

  float nm[4] = {0.f, 0.f, 0.f, 0.f};
  float q1[4] = {0.f, 0.f, 0.f, 0.f};
  float q2[4] = {0.f, 0.f, 0.f, 0.f};

  // one chunk (4 e-tiles, both sides): fold into nm/q1/q2
  auto compute = [&](int slot) {
#pragma unroll
    for (int et = 0; et < 4; ++et) {
      bf16x8 wa[4], wb[4];
#pragma unroll
      for (int s = 0; s < 4; ++s) {
        wa[s] = as_bf(*(const us8*)&ldsW[slot][et * 256 + s * 64 + lane]);
        wb[s] = as_bf(*(const us8*)&ldsW[slot][1024 + et * 256 + s * 64 + lane]);
      }
#pragma unroll
      for (int nt = 0; nt < 4; ++nt) {
        f32x4 a1 = zero4, a2 = zero4;
#pragma unroll
        for (int s = 0; s < 4; ++s)
          a1 = __builtin_amdgcn_mfma_f32_16x16x32_bf16(wa[s], xb[0][nt][s], a1, 0, 0, 0);
#pragma unroll
        for (int s = 0; s < 4; ++s)
          a2 = __builtin_amdgcn_mfma_f32_16x16x32_bf16(wb[s], xb[1][nt][s], a2, 0, 0, 0);
        nm[nt] += a1.x * a2.x + a1.y * a2.y + a1.z * a2.z + a1.w * a2.w;
        q1[nt] += a1.x * a1.x + a1.y * a1.y + a1.z * a1.z + a1.w * a1.w;
        q2[nt] += a2.x * a2.x + a2.y * a2.y + a2.z * a2.z + a2.w * a2.w;
      }
    }
  };

  // fully unrolled kk loop: all accP indexing static
#pragma unroll
  for (int kk = 0; kk < 4; ++kk) {
    const int cbase = kh * 8 + 2 * kk;
    __syncthreads();                       // chunk (kk,h=0) in slot0; slot1 free
    stage(cbase + 1, 1);
    compute(0);
    __syncthreads();                       // chunk (kk,h=1) in slot1; slot0 free
    if (kk < 3) stage(cbase + 2, 0);
    compute(1);

#pragma unroll
    for (int nt = 0; nt < 4; ++nt) {
      float n = nm[nt], s1 = q1[nt], s2 = q2[nt];
      n  += __shfl_xor(n, 16);  n  += __shfl_xor(n, 32);
      s1 += __shfl_xor(s1, 16); s1 += __shfl_xor(s1, 32);
      s2 += __shfl_xor(s2, 16); s2 += __shfl_xor(s2, 32);
      float d1 = fmaxf(sqrtf(s1), 1e-8f);
      float d2 = fmaxf(sqrtf(s2), 1e-8f);
      float p1 = n / (d1 * d2);
      // static element: accP[nt][kk]; garbage for lanes q!=kh (never stored)
      if (kk == 0)      accP[nt].x = fmaxf(accP[nt].x + p1, 0.f);
      else if (kk == 1) accP[nt].y = fmaxf(accP[nt].y + p1, 0.f);
      else if (kk == 2) accP[nt].z = fmaxf(accP[nt].z + p1, 0.f);
      else              accP[nt].w = fmaxf(accP[nt].w + p1, 0.f);
      nm[nt] = 0.f; q1[nt] = 0.f; q2[nt] = 0.f;
    }
  }

  if (q == kh) {
#pragma unroll
    for (int nt = 0; nt < 4; ++nt)
      *(f32x4*)(out + (size_t)(rowbase + nt * 16 + l15) * 16 + kh * 4) = accP[nt];
  }
}

extern "C" void kernel_launch(void* const* d_in, const int* in_sizes, int n_in,
                              void* d_out, int out_size, void* d_ws, size_t ws_size,
                              hipStream_t stream) {
  const float* x1 = (const float*)d_in[0];
  const float* x2 = (const float*)d_in[1];
  const float* W1 = (const float*)d_in[2];
  const float* W2 = (const float*)d_in[3];
  const float* V  = (const float*)d_in[4];
  const float* b  = (const float*)d_in[5];
  float* out = (float*)d_out;
  unsigned short* wsW = (unsigned short*)d_ws;
  unsigned short* wsV = wsW + (size_t)65536 * 8;   // 1MB offset

  ntn_prep_w<<<64, 256, 0, stream>>>(W1, W2, wsW);
  ntn_prep_v<<<2, 256, 0, stream>>>(V, wsV);
  ntn_main<<<512, 256, 0, stream>>>(x1, x2, b, wsW, wsV, out);
}